// Round 4
// baseline (265.342 us; speedup 1.0000x reference)
//
#include <hip/hip_runtime.h>
#include <math.h>

#define BB 4
#define CC 256
#define NN 4096
#define DQ 32
#define LOG2E 1.44269504f
#define TJ 128
#define PS_STRIDE 136   // 128 + 8 pad

typedef _Float16 half8 __attribute__((ext_vector_type(8)));
typedef _Float16 half4 __attribute__((ext_vector_type(4)));
typedef float float4v __attribute__((ext_vector_type(4)));

// ---------------- prep: W -> f16 (log2e folded into Wq/bq) ----------------
__global__ __launch_bounds__(64) void prep_kernel(
    const float* __restrict__ Wq, const float* __restrict__ bq,
    const float* __restrict__ Wk, const float* __restrict__ bk,
    const float* __restrict__ Wv, const float* __restrict__ bv,
    _Float16* __restrict__ Wh, float* __restrict__ bh)
{
    int o = blockIdx.x, t = threadIdx.x;
    const float* src; float scale = 1.0f, bias;
    if (o < DQ)            { src = Wq + o * CC;        scale = LOG2E; bias = bq[o] * LOG2E; }
    else if (o < 2 * DQ)   { src = Wk + (o - DQ) * CC;                bias = bk[o - DQ]; }
    else                   { src = Wv + (o - 2 * DQ) * CC;            bias = bv[o - 2 * DQ]; }
    float4 v = *(const float4*)(src + t * 4);
    half4 h = { (_Float16)(v.x * scale), (_Float16)(v.y * scale),
                (_Float16)(v.z * scale), (_Float16)(v.w * scale) };
    *(half4*)(Wh + o * CC + t * 4) = h;
    if (t == 0) bh[o] = bias;
}

// ---------------- proj: MFMA GEMM, 320 outputs x 32-pixel tile ----------------
// Qt/Kt: [b][n][32] f16 (n-major).  Vh: [b][c][n] f16.
__global__ __launch_bounds__(256) void proj_kernel(
    const float* __restrict__ x, const _Float16* __restrict__ Wh,
    const float* __restrict__ bh,
    _Float16* __restrict__ Qt, _Float16* __restrict__ Kt,
    _Float16* __restrict__ Vh)
{
    __shared__ _Float16 xl[32 * 256];     // [n][c], chunk-of-8 swizzle: chunk' = (c>>3) ^ n
    __shared__ _Float16 os_qk[32 * 72];   // [n][o<64 + pad]
    __shared__ _Float16 os_v[256 * 40];   // [c][n + pad]

    const int tid = threadIdx.x;
    const int lane = tid & 63, w = tid >> 6;
    const int i16 = lane & 15, q = lane >> 4;
    const int n0 = blockIdx.x * 32, b = blockIdx.y;

    // stage x tile -> f16 [n][c] via 4x4 in-register transpose
    const float* xb = x + (size_t)b * CC * NN + n0;
    #pragma unroll
    for (int u = 0; u < 2; ++u) {
        int c0 = 4 * (tid >> 3) + 128 * u;
        int nn = 4 * (tid & 7);
        float4 rr[4];
        #pragma unroll
        for (int j = 0; j < 4; ++j)
            rr[j] = *(const float4*)(xb + (size_t)(c0 + j) * NN + nn);
        #pragma unroll
        for (int e = 0; e < 4; ++e) {
            int n = nn + e;
            half4 h = { (_Float16)((const float*)&rr[0])[e],
                        (_Float16)((const float*)&rr[1])[e],
                        (_Float16)((const float*)&rr[2])[e],
                        (_Float16)((const float*)&rr[3])[e] };
            int chunk = (c0 >> 3) ^ (n & 31);
            *(half4*)&xl[n * 256 + chunk * 8 + (c0 & 7)] = h;
        }
    }

    float4v acc[5][2];
    const int obase = 80 * w;
    #pragma unroll
    for (int ot = 0; ot < 5; ++ot) {
        float4 b4 = *(const float4*)(bh + obase + 16 * ot + 4 * q);
        #pragma unroll
        for (int nt = 0; nt < 2; ++nt)
            acc[ot][nt] = (float4v){b4.x, b4.y, b4.z, b4.w};
    }
    __syncthreads();

    #pragma unroll
    for (int k = 0; k < 8; ++k) {
        half8 af[5], bf[2];
        #pragma unroll
        for (int ot = 0; ot < 5; ++ot)
            af[ot] = *(const half8*)(Wh + (size_t)(obase + 16 * ot + i16) * CC + k * 32 + 8 * q);
        #pragma unroll
        for (int nt = 0; nt < 2; ++nt) {
            int n = 16 * nt + i16;
            bf[nt] = *(const half8*)&xl[n * 256 + (((4 * k + q) ^ (n & 31)) * 8)];
        }
        #pragma unroll
        for (int ot = 0; ot < 5; ++ot)
            #pragma unroll
            for (int nt = 0; nt < 2; ++nt)
                acc[ot][nt] = __builtin_amdgcn_mfma_f32_16x16x32_f16(af[ot], bf[nt], acc[ot][nt], 0, 0, 0);
    }

    #pragma unroll
    for (int ot = 0; ot < 5; ++ot) {
        int og = obase + 16 * ot;
        #pragma unroll
        for (int nt = 0; nt < 2; ++nt) {
            int n = 16 * nt + i16;
            if (og < 64) {
                half4 hv = { (_Float16)acc[ot][nt][0], (_Float16)acc[ot][nt][1],
                             (_Float16)acc[ot][nt][2], (_Float16)acc[ot][nt][3] };
                *(half4*)&os_qk[n * 72 + og + 4 * q] = hv;
            } else {
                int cb = og - 64 + 4 * q;
                #pragma unroll
                for (int r = 0; r < 4; ++r)
                    os_v[(cb + r) * 40 + n] = (_Float16)acc[ot][nt][r];
            }
        }
    }
    __syncthreads();

    _Float16* Qtb = Qt + (size_t)b * NN * DQ;
    _Float16* Ktb = Kt + (size_t)b * NN * DQ;
    {
        int n = tid >> 3, p = tid & 7;
        half8 hv = *(const half8*)&os_qk[n * 72 + 8 * p];
        if (p < 4) *(half8*)(Qtb + (size_t)(n0 + n) * DQ + 8 * p) = hv;
        else       *(half8*)(Ktb + (size_t)(n0 + n) * DQ + 8 * (p - 4)) = hv;
    }
    _Float16* Vb = Vh + (size_t)b * CC * NN;
    #pragma unroll
    for (int u = 0; u < 4; ++u) {
        int c = u * 64 + (tid >> 2), p = tid & 3;
        half8 hv = *(const half8*)&os_v[c * 40 + 8 * p];
        *(half8*)(Vb + (size_t)c * NN + n0 + 8 * p) = hv;
    }
}

// ---------------- rowstat: l[q] = sum_j exp2(S[q][j]); LDS-free, barrier-free ----
// Block: 64 queries (16/wave), half the key range. K A-frags direct from global.
__global__ __launch_bounds__(256) void rowstat_kernel(
    const _Float16* __restrict__ Qt, const _Float16* __restrict__ Kt,
    float* __restrict__ L)
{
    const int tid = threadIdx.x;
    const int lane = tid & 63, w = tid >> 6;
    const int i16 = lane & 15, q = lane >> 4;
    const int q0 = blockIdx.x * 64, js = blockIdx.y, b = blockIdx.z;

    const _Float16* Qtb = Qt + (size_t)b * NN * DQ;
    const _Float16* Ktb = Kt + (size_t)b * NN * DQ;
    half8 qb = *(const half8*)(Qtb + (size_t)(q0 + 16 * w + i16) * DQ + 8 * q);

    float l = 0.f;
    #pragma unroll 2
    for (int j0 = js * (NN / 2); j0 < (js + 1) * (NN / 2); j0 += 64) {
        float4v s[4];
        #pragma unroll
        for (int jt = 0; jt < 4; ++jt) {
            half8 ka = *(const half8*)(Ktb + (size_t)(j0 + 16 * jt + i16) * DQ + 8 * q);
            float4v z = {0.f, 0.f, 0.f, 0.f};
            s[jt] = __builtin_amdgcn_mfma_f32_16x16x32_f16(ka, qb, z, 0, 0, 0);
        }
        #pragma unroll
        for (int jt = 0; jt < 4; ++jt)
            #pragma unroll
            for (int r = 0; r < 4; ++r)
                l += exp2f(s[jt][r]);
    }
    // sum the 4 quads (each holds different key rows of the same query)
    l += __shfl_xor(l, 16, 64);
    l += __shfl_xor(l, 32, 64);
    if (q == 0)
        L[((size_t)b * 2 + js) * NN + q0 + 16 * w + i16] = l;
}

// ---------------- attn: K/V frags direct from global, 1 barrier/tile ----------------
// Block: 32 queries; wave w owns channels [64w,64w+64) and S-strip keys [32w,32w+32).
// P double-buffered in LDS; P pre-normalized by 1/l (exp2(s - log2 l) <= 1, f16-safe).
__global__ __launch_bounds__(256) void attn_kernel(
    const float* __restrict__ x,
    const _Float16* __restrict__ Qt, const _Float16* __restrict__ Kt,
    const _Float16* __restrict__ Vh, const float* __restrict__ L,
    float* __restrict__ out)
{
    __shared__ _Float16 ps[2][32 * PS_STRIDE];

    const int tid = threadIdx.x;
    const int w = tid >> 6, lane = tid & 63;
    const int i16 = lane & 15, q = lane >> 4;
    // XCD swizzle: batch b pinned to XCDs {2b, 2b+1} (locality heuristic only)
    const int id = blockIdx.x;
    const int b = (id & 7) >> 1;
    const int i0 = 32 * ((id >> 3) + 64 * (id & 1));

    const _Float16* Ktb = Kt + (size_t)b * NN * DQ;
    const _Float16* Vb  = Vh + (size_t)b * CC * NN;

    float lg[2];
    #pragma unroll
    for (int it = 0; it < 2; ++it) {
        int qi = i0 + 16 * it + i16;
        float l0 = L[((size_t)b * 2 + 0) * NN + qi];
        float l1 = L[((size_t)b * 2 + 1) * NN + qi];
        lg[it] = log2f(l0 + l1);
    }

    half8 qb[2];
    {
        const _Float16* Qtb = Qt + (size_t)b * NN * DQ;
        qb[0] = *(const half8*)(Qtb + (size_t)(i0 + i16) * DQ + 8 * q);
        qb[1] = *(const half8*)(Qtb + (size_t)(i0 + 16 + i16) * DQ + 8 * q);
    }

    float4v O[4][2];
    #pragma unroll
    for (int ct = 0; ct < 4; ++ct)
        #pragma unroll
        for (int it = 0; it < 2; ++it)
            O[ct][it] = (float4v){0.f, 0.f, 0.f, 0.f};

    for (int t = 0; t < NN / TJ; ++t) {
        const int j0 = t * TJ;
        _Float16* psb = &ps[t & 1][0];

        // ---- S phase: wave-private strips, K direct from global ----
        #pragma unroll
        for (int st = 0; st < 2; ++st) {
            int j = j0 + 32 * w + 16 * st + i16;
            half8 ka = *(const half8*)(Ktb + (size_t)j * DQ + 8 * q);
            #pragma unroll
            for (int it = 0; it < 2; ++it) {
                float4v z = {0.f, 0.f, 0.f, 0.f};
                float4v s = __builtin_amdgcn_mfma_f32_16x16x32_f16(ka, qb[it], z, 0, 0, 0);
                half4 hv = { (_Float16)exp2f(s[0] - lg[it]),
                             (_Float16)exp2f(s[1] - lg[it]),
                             (_Float16)exp2f(s[2] - lg[it]),
                             (_Float16)exp2f(s[3] - lg[it]) };
                *(half4*)&psb[(16 * it + i16) * PS_STRIDE + 32 * w + 16 * st + 4 * q] = hv;
            }
        }
        __syncthreads();   // the only barrier: P strips visible to all waves

        // ---- PV: V A-frags direct from global (L2-resident) ----
        half8 pb[4][2];
        #pragma unroll
        for (int ks = 0; ks < 4; ++ks)
            #pragma unroll
            for (int it = 0; it < 2; ++it)
                pb[ks][it] = *(const half8*)&psb[(16 * it + i16) * PS_STRIDE + 32 * ks + 8 * q];
        #pragma unroll
        for (int ct = 0; ct < 4; ++ct) {
            int c = 64 * w + 16 * ct + i16;
            const _Float16* vrow = Vb + (size_t)c * NN + j0;
            #pragma unroll
            for (int ks = 0; ks < 4; ++ks) {
                half8 va = *(const half8*)(vrow + 32 * ks + 8 * q);
                #pragma unroll
                for (int it = 0; it < 2; ++it)
                    O[ct][it] = __builtin_amdgcn_mfma_f32_16x16x32_f16(va, pb[ks][it], O[ct][it], 0, 0, 0);
            }
        }
    }

    // epilogue: O already normalized; residual add
    const float* xb = x + (size_t)b * CC * NN;
    float* ob = out + (size_t)b * CC * NN;
    #pragma unroll
    for (int ct = 0; ct < 4; ++ct)
        #pragma unroll
        for (int it = 0; it < 2; ++it)
            #pragma unroll
            for (int r = 0; r < 4; ++r) {
                int c = 64 * w + 16 * ct + 4 * q + r;
                size_t idx = (size_t)c * NN + i0 + 16 * it + i16;
                ob[idx] = xb[idx] + O[ct][it][r];
            }
}

extern "C" void kernel_launch(void* const* d_in, const int* in_sizes, int n_in,
                              void* d_out, int out_size, void* d_ws, size_t ws_size,
                              hipStream_t stream) {
    const float* x  = (const float*)d_in[0];
    const float* Wq = (const float*)d_in[1];
    const float* bq = (const float*)d_in[2];
    const float* Wk = (const float*)d_in[3];
    const float* bk = (const float*)d_in[4];
    const float* Wv = (const float*)d_in[5];
    const float* bv = (const float*)d_in[6];
    float* out = (float*)d_out;

    char* ws = (char*)d_ws;
    _Float16* Wh = (_Float16*)(ws);                 // 320*256*2 = 163840
    float*    bh = (float*)(ws + 163840);           // 1280
    _Float16* Qt = (_Float16*)(ws + 262144);        // 1 MB
    _Float16* Kt = (_Float16*)(ws + 1310720);       // 1 MB
    _Float16* Vh = (_Float16*)(ws + 2359296);       // 8 MB
    float*    L  = (float*)(ws + 10747904);         // 4*2*4096*4 = 128 KB

    prep_kernel<<<dim3(320), 64, 0, stream>>>(Wq, bq, Wk, bk, Wv, bv, Wh, bh);
    proj_kernel<<<dim3(NN / 32, BB), 256, 0, stream>>>(x, Wh, bh, Qt, Kt, Vh);
    rowstat_kernel<<<dim3(NN / 64, 2, BB), 256, 0, stream>>>(Qt, Kt, L);
    attn_kernel<<<dim3(512), 256, 0, stream>>>(x, Qt, Kt, Vh, L, out);
}

// Round 5
// 248.842 us; speedup vs baseline: 1.0663x; 1.0663x over previous
//
#include <hip/hip_runtime.h>
#include <math.h>

#define BB 4
#define CC 256
#define NN 4096
#define DQ 32
#define LOG2E 1.44269504f
#define PS_STRIDE 136   // 128 + 8 pad

typedef _Float16 half8 __attribute__((ext_vector_type(8)));
typedef _Float16 half4 __attribute__((ext_vector_type(4)));
typedef float float4v __attribute__((ext_vector_type(4)));

// ---------------- prep: W -> f16 (log2e folded into Wq/bq) ----------------
__global__ __launch_bounds__(64) void prep_kernel(
    const float* __restrict__ Wq, const float* __restrict__ bq,
    const float* __restrict__ Wk, const float* __restrict__ bk,
    const float* __restrict__ Wv, const float* __restrict__ bv,
    _Float16* __restrict__ Wh, float* __restrict__ bh)
{
    int o = blockIdx.x, t = threadIdx.x;
    const float* src; float scale = 1.0f, bias;
    if (o < DQ)            { src = Wq + o * CC;        scale = LOG2E; bias = bq[o] * LOG2E; }
    else if (o < 2 * DQ)   { src = Wk + (o - DQ) * CC;                bias = bk[o - DQ]; }
    else                   { src = Wv + (o - 2 * DQ) * CC;            bias = bv[o - 2 * DQ]; }
    float4 v = *(const float4*)(src + t * 4);
    half4 h = { (_Float16)(v.x * scale), (_Float16)(v.y * scale),
                (_Float16)(v.z * scale), (_Float16)(v.w * scale) };
    *(half4*)(Wh + o * CC + t * 4) = h;
    if (t == 0) bh[o] = bias;
}

// ---------------- proj: MFMA GEMM, 320 outputs x 32-pixel tile ----------------
// Qt/Kt: [b][n][32] f16 (n-major).  Vh: [b][c][n] f16.
// k-loop software-pipelined: W frags for k+1 prefetched during k.
__global__ __launch_bounds__(256) void proj_kernel(
    const float* __restrict__ x, const _Float16* __restrict__ Wh,
    const float* __restrict__ bh,
    _Float16* __restrict__ Qt, _Float16* __restrict__ Kt,
    _Float16* __restrict__ Vh)
{
    __shared__ _Float16 xl[32 * 256];     // [n][c], chunk-of-8 swizzle
    __shared__ _Float16 os_qk[32 * 72];
    __shared__ _Float16 os_v[256 * 40];

    const int tid = threadIdx.x;
    const int lane = tid & 63, w = tid >> 6;
    const int i16 = lane & 15, q = lane >> 4;
    const int n0 = blockIdx.x * 32, b = blockIdx.y;

    const float* xb = x + (size_t)b * CC * NN + n0;
    #pragma unroll
    for (int u = 0; u < 2; ++u) {
        int c0 = 4 * (tid >> 3) + 128 * u;
        int nn = 4 * (tid & 7);
        float4 rr[4];
        #pragma unroll
        for (int j = 0; j < 4; ++j)
            rr[j] = *(const float4*)(xb + (size_t)(c0 + j) * NN + nn);
        #pragma unroll
        for (int e = 0; e < 4; ++e) {
            int n = nn + e;
            half4 h = { (_Float16)((const float*)&rr[0])[e],
                        (_Float16)((const float*)&rr[1])[e],
                        (_Float16)((const float*)&rr[2])[e],
                        (_Float16)((const float*)&rr[3])[e] };
            int chunk = (c0 >> 3) ^ (n & 31);
            *(half4*)&xl[n * 256 + chunk * 8 + (c0 & 7)] = h;
        }
    }

    float4v acc[5][2];
    const int obase = 80 * w;
    #pragma unroll
    for (int ot = 0; ot < 5; ++ot) {
        float4 b4 = *(const float4*)(bh + obase + 16 * ot + 4 * q);
        #pragma unroll
        for (int nt = 0; nt < 2; ++nt)
            acc[ot][nt] = (float4v){b4.x, b4.y, b4.z, b4.w};
    }

    const _Float16* wbase = Wh + (size_t)(obase + i16) * CC + 8 * q;
    half8 afc[5];
    #pragma unroll
    for (int ot = 0; ot < 5; ++ot)
        afc[ot] = *(const half8*)(wbase + (size_t)16 * ot * CC);
    __syncthreads();

    #pragma unroll
    for (int k = 0; k < 8; ++k) {
        half8 afn[5];
        int kn = (k + 1) & 7;
        #pragma unroll
        for (int ot = 0; ot < 5; ++ot)
            afn[ot] = *(const half8*)(wbase + (size_t)16 * ot * CC + kn * 32);
        half8 bf[2];
        #pragma unroll
        for (int nt = 0; nt < 2; ++nt) {
            int n = 16 * nt + i16;
            bf[nt] = *(const half8*)&xl[n * 256 + (((4 * k + q) ^ (n & 31)) * 8)];
        }
        #pragma unroll
        for (int ot = 0; ot < 5; ++ot)
            #pragma unroll
            for (int nt = 0; nt < 2; ++nt)
                acc[ot][nt] = __builtin_amdgcn_mfma_f32_16x16x32_f16(afc[ot], bf[nt], acc[ot][nt], 0, 0, 0);
        #pragma unroll
        for (int ot = 0; ot < 5; ++ot)
            afc[ot] = afn[ot];
    }

    #pragma unroll
    for (int ot = 0; ot < 5; ++ot) {
        int og = obase + 16 * ot;
        #pragma unroll
        for (int nt = 0; nt < 2; ++nt) {
            int n = 16 * nt + i16;
            if (og < 64) {
                half4 hv = { (_Float16)acc[ot][nt][0], (_Float16)acc[ot][nt][1],
                             (_Float16)acc[ot][nt][2], (_Float16)acc[ot][nt][3] };
                *(half4*)&os_qk[n * 72 + og + 4 * q] = hv;
            } else {
                int cb = og - 64 + 4 * q;
                #pragma unroll
                for (int r = 0; r < 4; ++r)
                    os_v[(cb + r) * 40 + n] = (_Float16)acc[ot][nt][r];
            }
        }
    }
    __syncthreads();

    _Float16* Qtb = Qt + (size_t)b * NN * DQ;
    _Float16* Ktb = Kt + (size_t)b * NN * DQ;
    {
        int n = tid >> 3, p = tid & 7;
        half8 hv = *(const half8*)&os_qk[n * 72 + 8 * p];
        if (p < 4) *(half8*)(Qtb + (size_t)(n0 + n) * DQ + 8 * p) = hv;
        else       *(half8*)(Ktb + (size_t)(n0 + n) * DQ + 8 * (p - 4)) = hv;
    }
    _Float16* Vb = Vh + (size_t)b * CC * NN;
    #pragma unroll
    for (int u = 0; u < 4; ++u) {
        int c = u * 64 + (tid >> 2), p = tid & 3;
        half8 hv = *(const half8*)&os_v[c * 40 + 8 * p];
        *(half8*)(Vb + (size_t)c * NN + n0 + 8 * p) = hv;
    }
}

// ---------------- rowstat: l[q] = sum_j exp2(S[q][j]) over a key quarter ----
// LDS-free, barrier-free; K frags register-pipelined 1 tile ahead.
#define RS_TILE(KC, KN, U)                                                     \
    {                                                                          \
        const int un = ((U) + 1) & 15;                                         \
        _Pragma("unroll")                                                      \
        for (int jt = 0; jt < 4; ++jt)                                         \
            KN[jt] = *(const half8*)(kb0 + un * 64 * DQ + jt * 16 * DQ);       \
        _Pragma("unroll")                                                      \
        for (int jt = 0; jt < 4; ++jt) {                                       \
            float4v z = {0.f, 0.f, 0.f, 0.f};                                  \
            float4v s = __builtin_amdgcn_mfma_f32_16x16x32_f16(KC[jt], qb, z, 0, 0, 0); \
            l += exp2f(s[0]); l += exp2f(s[1]);                                \
            l += exp2f(s[2]); l += exp2f(s[3]);                                \
        }                                                                      \
    }

__global__ __launch_bounds__(256) void rowstat_kernel(
    const _Float16* __restrict__ Qt, const _Float16* __restrict__ Kt,
    float* __restrict__ L)
{
    const int tid = threadIdx.x;
    const int lane = tid & 63, w = tid >> 6;
    const int i16 = lane & 15, q = lane >> 4;
    const int q0 = blockIdx.x * 64, js = blockIdx.y, b = blockIdx.z;

    const _Float16* Qtb = Qt + (size_t)b * NN * DQ;
    const _Float16* Ktb = Kt + (size_t)b * NN * DQ;
    half8 qb = *(const half8*)(Qtb + (size_t)(q0 + 16 * w + i16) * DQ + 8 * q);
    const _Float16* kb0 = Ktb + (size_t)(js * 1024 + i16) * DQ + 8 * q;

    float l = 0.f;
    half8 kA[4], kB[4];
    #pragma unroll
    for (int jt = 0; jt < 4; ++jt)
        kA[jt] = *(const half8*)(kb0 + jt * 16 * DQ);
    for (int uu = 0; uu < 8; ++uu) {
        RS_TILE(kA, kB, 2 * uu);
        RS_TILE(kB, kA, 2 * uu + 1);
    }
    l += __shfl_xor(l, 16, 64);
    l += __shfl_xor(l, 32, 64);
    if (q == 0)
        L[((size_t)b * 4 + js) * NN + q0 + 16 * w + i16] = l;
}

// ---------------- attn: register-pipelined, 1 lgkm-only barrier/tile ----------------
// 1024 blocks: (b, channel-half h) pinned per XCD; block = 32 queries x 128 channels.
// Wave w: channels [128h+32w, +32), S-strip keys [j0+32w, +32). P double-buffered.
#define ATTN_TILE(KC, VC, KN, VN, T)                                           \
    {                                                                          \
        const int tn = ((T) + 1) & 31;                                         \
        _Pragma("unroll")                                                      \
        for (int st = 0; st < 2; ++st)                                         \
            KN[st] = *(const half8*)(kbase[st] + tn * 128 * DQ);               \
        _Pragma("unroll")                                                      \
        for (int ct = 0; ct < 2; ++ct)                                         \
            _Pragma("unroll")                                                  \
            for (int ks = 0; ks < 4; ++ks)                                     \
                VN[ct][ks] = *(const half8*)(vbase[ct] + tn * 128 + 32 * ks);  \
        _Float16* psb = &ps[(T) & 1][0];                                       \
        _Pragma("unroll")                                                      \
        for (int st = 0; st < 2; ++st)                                         \
            _Pragma("unroll")                                                  \
            for (int it = 0; it < 2; ++it) {                                   \
                float4v z = {0.f, 0.f, 0.f, 0.f};                              \
                float4v s = __builtin_amdgcn_mfma_f32_16x16x32_f16(KC[st], qb[it], z, 0, 0, 0); \
                half4 hv = { (_Float16)exp2f(s[0] - lg[it]),                   \
                             (_Float16)exp2f(s[1] - lg[it]),                   \
                             (_Float16)exp2f(s[2] - lg[it]),                   \
                             (_Float16)exp2f(s[3] - lg[it]) };                 \
                *(half4*)&psb[(16 * it + i16) * PS_STRIDE + 32 * w + 16 * st + 4 * q] = hv; \
            }                                                                  \
        asm volatile("s_waitcnt lgkmcnt(0)\n\ts_barrier" ::: "memory");        \
        half8 pb[4][2];                                                        \
        _Pragma("unroll")                                                      \
        for (int ks = 0; ks < 4; ++ks)                                         \
            _Pragma("unroll")                                                  \
            for (int it = 0; it < 2; ++it)                                     \
                pb[ks][it] = *(const half8*)&psb[(16 * it + i16) * PS_STRIDE + 32 * ks + 8 * q]; \
        _Pragma("unroll")                                                      \
        for (int ct = 0; ct < 2; ++ct)                                         \
            _Pragma("unroll")                                                  \
            for (int ks = 0; ks < 4; ++ks)                                     \
                _Pragma("unroll")                                              \
                for (int it = 0; it < 2; ++it)                                 \
                    O[ct][it] = __builtin_amdgcn_mfma_f32_16x16x32_f16(VC[ct][ks], pb[ks][it], O[ct][it], 0, 0, 0); \
    }

__global__ __launch_bounds__(256) void attn_kernel(
    const float* __restrict__ x,
    const _Float16* __restrict__ Qt, const _Float16* __restrict__ Kt,
    const _Float16* __restrict__ Vh, const float* __restrict__ L,
    float* __restrict__ out)
{
    __shared__ _Float16 ps[2][32 * PS_STRIDE];

    const int tid = threadIdx.x;
    const int w = tid >> 6, lane = tid & 63;
    const int i16 = lane & 15, q = lane >> 4;
    // id%8 -> (h,b): pins each (batch, channel-half) to one XCD (round-robin heuristic)
    const int id = blockIdx.x;
    const int h = id & 1;
    const int b = (id >> 1) & 3;
    const int i0 = 32 * (id >> 3);

    const _Float16* Ktb = Kt + (size_t)b * NN * DQ;
    const _Float16* Vb  = Vh + (size_t)b * CC * NN;

    float lg[2];
    #pragma unroll
    for (int it = 0; it < 2; ++it) {
        int qi = i0 + 16 * it + i16;
        float l = 0.f;
        #pragma unroll
        for (int js = 0; js < 4; ++js)
            l += L[((size_t)b * 4 + js) * NN + qi];
        lg[it] = log2f(l);
    }

    half8 qb[2];
    {
        const _Float16* Qtb = Qt + (size_t)b * NN * DQ;
        qb[0] = *(const half8*)(Qtb + (size_t)(i0 + i16) * DQ + 8 * q);
        qb[1] = *(const half8*)(Qtb + (size_t)(i0 + 16 + i16) * DQ + 8 * q);
    }

    const _Float16* kbase[2];
    #pragma unroll
    for (int st = 0; st < 2; ++st)
        kbase[st] = Ktb + (size_t)(32 * w + 16 * st + i16) * DQ + 8 * q;
    const _Float16* vbase[2];
    #pragma unroll
    for (int ct = 0; ct < 2; ++ct)
        vbase[ct] = Vb + (size_t)(128 * h + 32 * w + 16 * ct + i16) * NN + 8 * q;

    float4v O[2][2];
    #pragma unroll
    for (int ct = 0; ct < 2; ++ct)
        #pragma unroll
        for (int it = 0; it < 2; ++it)
            O[ct][it] = (float4v){0.f, 0.f, 0.f, 0.f};

    half8 kaA[2], kaB[2], vaA[2][4], vaB[2][4];
    #pragma unroll
    for (int st = 0; st < 2; ++st)
        kaA[st] = *(const half8*)(kbase[st]);
    #pragma unroll
    for (int ct = 0; ct < 2; ++ct)
        #pragma unroll
        for (int ks = 0; ks < 4; ++ks)
            vaA[ct][ks] = *(const half8*)(vbase[ct] + 32 * ks);

    for (int tt = 0; tt < 16; ++tt) {
        ATTN_TILE(kaA, vaA, kaB, vaB, 2 * tt);
        ATTN_TILE(kaB, vaB, kaA, vaA, 2 * tt + 1);
    }

    // epilogue: O already normalized (P = exp2(s - log2 l)); residual add
    const float* xb = x + (size_t)b * CC * NN;
    float* ob = out + (size_t)b * CC * NN;
    #pragma unroll
    for (int ct = 0; ct < 2; ++ct)
        #pragma unroll
        for (int it = 0; it < 2; ++it)
            #pragma unroll
            for (int r = 0; r < 4; ++r) {
                int c = 128 * h + 32 * w + 16 * ct + 4 * q + r;
                size_t idx = (size_t)c * NN + i0 + 16 * it + i16;
                ob[idx] = xb[idx] + O[ct][it][r];
            }
}

extern "C" void kernel_launch(void* const* d_in, const int* in_sizes, int n_in,
                              void* d_out, int out_size, void* d_ws, size_t ws_size,
                              hipStream_t stream) {
    const float* x  = (const float*)d_in[0];
    const float* Wq = (const float*)d_in[1];
    const float* bq = (const float*)d_in[2];
    const float* Wk = (const float*)d_in[3];
    const float* bk = (const float*)d_in[4];
    const float* Wv = (const float*)d_in[5];
    const float* bv = (const float*)d_in[6];
    float* out = (float*)d_out;

    char* ws = (char*)d_ws;
    _Float16* Wh = (_Float16*)(ws);                 // 320*256*2 = 163840
    float*    bh = (float*)(ws + 163840);           // 1280
    _Float16* Qt = (_Float16*)(ws + 262144);        // 1 MB
    _Float16* Kt = (_Float16*)(ws + 1310720);       // 1 MB
    _Float16* Vh = (_Float16*)(ws + 2359296);       // 8 MB
    float*    L  = (float*)(ws + 10747904);         // 4*4*4096*4 = 256 KB

    prep_kernel<<<dim3(320), 64, 0, stream>>>(Wq, bq, Wk, bk, Wv, bv, Wh, bh);
    proj_kernel<<<dim3(NN / 32, BB), 256, 0, stream>>>(x, Wh, bh, Qt, Kt, Vh);
    rowstat_kernel<<<dim3(NN / 64, 4, BB), 256, 0, stream>>>(Qt, Kt, L);
    attn_kernel<<<dim3(1024), 256, 0, stream>>>(x, Qt, Kt, Vh, L, out);
}

// Round 6
// 234.010 us; speedup vs baseline: 1.1339x; 1.0634x over previous
//
#include <hip/hip_runtime.h>
#include <math.h>

#define BB 4
#define CC 256
#define NN 4096
#define DQ 32
#define LOG2E 1.44269504f

typedef _Float16 half8 __attribute__((ext_vector_type(8)));
typedef _Float16 half4 __attribute__((ext_vector_type(4)));
typedef float float4v __attribute__((ext_vector_type(4)));

// ---------------- prep: W -> f16 (log2e folded into Wq/bq) ----------------
__global__ __launch_bounds__(64) void prep_kernel(
    const float* __restrict__ Wq, const float* __restrict__ bq,
    const float* __restrict__ Wk, const float* __restrict__ bk,
    const float* __restrict__ Wv, const float* __restrict__ bv,
    _Float16* __restrict__ Wh, float* __restrict__ bh)
{
    int o = blockIdx.x, t = threadIdx.x;
    const float* src; float scale = 1.0f, bias;
    if (o < DQ)            { src = Wq + o * CC;        scale = LOG2E; bias = bq[o] * LOG2E; }
    else if (o < 2 * DQ)   { src = Wk + (o - DQ) * CC;                bias = bk[o - DQ]; }
    else                   { src = Wv + (o - 2 * DQ) * CC;            bias = bv[o - 2 * DQ]; }
    float4 v = *(const float4*)(src + t * 4);
    half4 h = { (_Float16)(v.x * scale), (_Float16)(v.y * scale),
                (_Float16)(v.z * scale), (_Float16)(v.w * scale) };
    *(half4*)(Wh + o * CC + t * 4) = h;
    if (t == 0) bh[o] = bias;
}

// ---------------- proj: MFMA GEMM, 320 outputs x 32-pixel tile (unchanged R5) ----
__global__ __launch_bounds__(256) void proj_kernel(
    const float* __restrict__ x, const _Float16* __restrict__ Wh,
    const float* __restrict__ bh,
    _Float16* __restrict__ Qt, _Float16* __restrict__ Kt,
    _Float16* __restrict__ Vh)
{
    __shared__ _Float16 xl[32 * 256];
    __shared__ _Float16 os_qk[32 * 72];
    __shared__ _Float16 os_v[256 * 40];

    const int tid = threadIdx.x;
    const int lane = tid & 63, w = tid >> 6;
    const int i16 = lane & 15, q = lane >> 4;
    const int n0 = blockIdx.x * 32, b = blockIdx.y;

    const float* xb = x + (size_t)b * CC * NN + n0;
    #pragma unroll
    for (int u = 0; u < 2; ++u) {
        int c0 = 4 * (tid >> 3) + 128 * u;
        int nn = 4 * (tid & 7);
        float4 rr[4];
        #pragma unroll
        for (int j = 0; j < 4; ++j)
            rr[j] = *(const float4*)(xb + (size_t)(c0 + j) * NN + nn);
        #pragma unroll
        for (int e = 0; e < 4; ++e) {
            int n = nn + e;
            half4 h = { (_Float16)((const float*)&rr[0])[e],
                        (_Float16)((const float*)&rr[1])[e],
                        (_Float16)((const float*)&rr[2])[e],
                        (_Float16)((const float*)&rr[3])[e] };
            int chunk = (c0 >> 3) ^ (n & 31);
            *(half4*)&xl[n * 256 + chunk * 8 + (c0 & 7)] = h;
        }
    }

    float4v acc[5][2];
    const int obase = 80 * w;
    #pragma unroll
    for (int ot = 0; ot < 5; ++ot) {
        float4 b4 = *(const float4*)(bh + obase + 16 * ot + 4 * q);
        #pragma unroll
        for (int nt = 0; nt < 2; ++nt)
            acc[ot][nt] = (float4v){b4.x, b4.y, b4.z, b4.w};
    }

    const _Float16* wbase = Wh + (size_t)(obase + i16) * CC + 8 * q;
    half8 afc[5];
    #pragma unroll
    for (int ot = 0; ot < 5; ++ot)
        afc[ot] = *(const half8*)(wbase + (size_t)16 * ot * CC);
    __syncthreads();

    #pragma unroll
    for (int k = 0; k < 8; ++k) {
        half8 afn[5];
        int kn = (k + 1) & 7;
        #pragma unroll
        for (int ot = 0; ot < 5; ++ot)
            afn[ot] = *(const half8*)(wbase + (size_t)16 * ot * CC + kn * 32);
        half8 bf[2];
        #pragma unroll
        for (int nt = 0; nt < 2; ++nt) {
            int n = 16 * nt + i16;
            bf[nt] = *(const half8*)&xl[n * 256 + (((4 * k + q) ^ (n & 31)) * 8)];
        }
        #pragma unroll
        for (int ot = 0; ot < 5; ++ot)
            #pragma unroll
            for (int nt = 0; nt < 2; ++nt)
                acc[ot][nt] = __builtin_amdgcn_mfma_f32_16x16x32_f16(afc[ot], bf[nt], acc[ot][nt], 0, 0, 0);
        #pragma unroll
        for (int ot = 0; ot < 5; ++ot)
            afc[ot] = afn[ot];
    }

    #pragma unroll
    for (int ot = 0; ot < 5; ++ot) {
        int og = obase + 16 * ot;
        #pragma unroll
        for (int nt = 0; nt < 2; ++nt) {
            int n = 16 * nt + i16;
            if (og < 64) {
                half4 hv = { (_Float16)acc[ot][nt][0], (_Float16)acc[ot][nt][1],
                             (_Float16)acc[ot][nt][2], (_Float16)acc[ot][nt][3] };
                *(half4*)&os_qk[n * 72 + og + 4 * q] = hv;
            } else {
                int cb = og - 64 + 4 * q;
                #pragma unroll
                for (int r = 0; r < 4; ++r)
                    os_v[(cb + r) * 40 + n] = (_Float16)acc[ot][nt][r];
            }
        }
    }
    __syncthreads();

    _Float16* Qtb = Qt + (size_t)b * NN * DQ;
    _Float16* Ktb = Kt + (size_t)b * NN * DQ;
    {
        int n = tid >> 3, p = tid & 7;
        half8 hv = *(const half8*)&os_qk[n * 72 + 8 * p];
        if (p < 4) *(half8*)(Qtb + (size_t)(n0 + n) * DQ + 8 * p) = hv;
        else       *(half8*)(Ktb + (size_t)(n0 + n) * DQ + 8 * (p - 4)) = hv;
    }
    _Float16* Vb = Vh + (size_t)b * CC * NN;
    #pragma unroll
    for (int u = 0; u < 4; ++u) {
        int c = u * 64 + (tid >> 2), p = tid & 3;
        half8 hv = *(const half8*)&os_v[c * 40 + 8 * p];
        *(half8*)(Vb + (size_t)c * NN + n0 + 8 * p) = hv;
    }
}

// ---------------- rowstat (unchanged R5) ----------------
#define RS_TILE(KC, KN, U)                                                     \
    {                                                                          \
        const int un = ((U) + 1) & 15;                                         \
        _Pragma("unroll")                                                      \
        for (int jt = 0; jt < 4; ++jt)                                         \
            KN[jt] = *(const half8*)(kb0 + un * 64 * DQ + jt * 16 * DQ);       \
        _Pragma("unroll")                                                      \
        for (int jt = 0; jt < 4; ++jt) {                                       \
            float4v z = {0.f, 0.f, 0.f, 0.f};                                  \
            float4v s = __builtin_amdgcn_mfma_f32_16x16x32_f16(KC[jt], qb, z, 0, 0, 0); \
            l += exp2f(s[0]); l += exp2f(s[1]);                                \
            l += exp2f(s[2]); l += exp2f(s[3]);                                \
        }                                                                      \
    }

__global__ __launch_bounds__(256) void rowstat_kernel(
    const _Float16* __restrict__ Qt, const _Float16* __restrict__ Kt,
    float* __restrict__ L)
{
    const int tid = threadIdx.x;
    const int lane = tid & 63, w = tid >> 6;
    const int i16 = lane & 15, q = lane >> 4;
    const int q0 = blockIdx.x * 64, js = blockIdx.y, b = blockIdx.z;

    const _Float16* Qtb = Qt + (size_t)b * NN * DQ;
    const _Float16* Ktb = Kt + (size_t)b * NN * DQ;
    half8 qb = *(const half8*)(Qtb + (size_t)(q0 + 16 * w + i16) * DQ + 8 * q);
    const _Float16* kb0 = Ktb + (size_t)(js * 1024 + i16) * DQ + 8 * q;

    float l = 0.f;
    half8 kA[4], kB[4];
    #pragma unroll
    for (int jt = 0; jt < 4; ++jt)
        kA[jt] = *(const half8*)(kb0 + jt * 16 * DQ);
    for (int uu = 0; uu < 8; ++uu) {
        RS_TILE(kA, kB, 2 * uu);
        RS_TILE(kB, kA, 2 * uu + 1);
    }
    l += __shfl_xor(l, 16, 64);
    l += __shfl_xor(l, 32, 64);
    if (q == 0)
        L[((size_t)b * 4 + js) * NN + q0 + 16 * w + i16] = l;
}

// ---------------- attn: P stays in registers (16x16x16 PV), K/V LDS dbuf ----------
// Block: 512 thr = 8 waves = 2 wq (query halves) x 4 wc (64-channel groups);
// covers 64 queries x 256 channels. Sᵀ per wave (C-layout row j=4q+r) feeds the
// PV MFMA B-operand (k=4q+e) DIRECTLY after exp2 — no P LDS traffic, no P barrier.
// K/V staged in swizzled double-buffered LDS; ONE barrier per 32-key tile.
#define STAGE_LOAD(TT)                                                          \
    {                                                                           \
        const int j0s = (TT) * 32;                                              \
        _Pragma("unroll")                                                       \
        for (int u = 0; u < 2; ++u) {                                           \
            int idx = u * 512 + tid;                                            \
            int c = idx >> 2, jc = idx & 3;                                     \
            gv[u] = *(const half8*)(Vb + (size_t)c * NN + j0s + jc * 8);        \
        }                                                                       \
        if (tid < 128) {                                                        \
            int j = tid >> 2, dc = tid & 3;                                     \
            gk = *(const half8*)(Ktb + (size_t)(j0s + j) * DQ + dc * 8);        \
        }                                                                       \
    }

#define STAGE_WRITE(BUF)                                                        \
    {                                                                           \
        _Pragma("unroll")                                                       \
        for (int u = 0; u < 2; ++u) {                                           \
            int idx = u * 512 + tid;                                            \
            int c = idx >> 2, jc = idx & 3;                                     \
            *(half8*)&v_lds[BUF][c * 32 + ((jc ^ (c & 3)) * 8)] = gv[u];        \
        }                                                                       \
        if (tid < 128) {                                                        \
            int j = tid >> 2, dc = tid & 3;                                     \
            *(half8*)&k_lds[BUF][j * 32 + ((dc ^ (j & 3)) * 8)] = gk;           \
        }                                                                       \
    }

__global__ __launch_bounds__(512) void attn_kernel(
    const float* __restrict__ x,
    const _Float16* __restrict__ Qt, const _Float16* __restrict__ Kt,
    const _Float16* __restrict__ Vh, const float* __restrict__ L,
    float* __restrict__ out)
{
    __shared__ _Float16 k_lds[2][32 * 32];    // [j][d-chunk16 ^ (j&3)]   2 KB x2
    __shared__ _Float16 v_lds[2][256 * 32];   // [c][j-chunk16 ^ (c&3)]  16 KB x2

    const int tid = threadIdx.x;
    const int w = tid >> 6, lane = tid & 63;
    const int i16 = lane & 15, q = lane >> 4;
    const int wq = w >> 2, wc = w & 3;
    // XCD swizzle: batch b -> XCDs {2b,2b+1}; 64 blocks per batch.
    const int id = blockIdx.x;
    const int b = (id & 7) >> 1;
    const int i0 = 64 * ((id >> 3) * 2 + (id & 1));
    const int qbase = i0 + 32 * wq;

    const _Float16* Ktb = Kt + (size_t)b * NN * DQ;
    const _Float16* Vb  = Vh + (size_t)b * CC * NN;

    float lg[2];
    #pragma unroll
    for (int it = 0; it < 2; ++it) {
        int qi = qbase + 16 * it + i16;
        float l = 0.f;
        #pragma unroll
        for (int js = 0; js < 4; ++js)
            l += L[((size_t)b * 4 + js) * NN + qi];
        lg[it] = log2f(l);
    }

    half8 qb[2];
    {
        const _Float16* Qtb = Qt + (size_t)b * NN * DQ;
        qb[0] = *(const half8*)(Qtb + (size_t)(qbase + i16) * DQ + 8 * q);
        qb[1] = *(const half8*)(Qtb + (size_t)(qbase + 16 + i16) * DQ + 8 * q);
    }

    float4v O[4][2];
    #pragma unroll
    for (int ct = 0; ct < 4; ++ct)
        #pragma unroll
        for (int it = 0; it < 2; ++it)
            O[ct][it] = (float4v){0.f, 0.f, 0.f, 0.f};

    half8 gv[2], gk;
    STAGE_LOAD(0);
    STAGE_WRITE(0);
    __syncthreads();

    for (int t = 0; t < NN / 32; ++t) {
        const int cur = t & 1;
        if (t < NN / 32 - 1) STAGE_LOAD(t + 1);

        // K A-fragments from LDS (swizzled, b128)
        half8 ka[2];
        #pragma unroll
        for (int jt = 0; jt < 2; ++jt) {
            int j = 16 * jt + i16;
            ka[jt] = *(const half8*)&k_lds[cur][j * 32 + ((q ^ (j & 3)) * 8)];
        }

        #pragma unroll
        for (int jt = 0; jt < 2; ++jt) {
            // Sᵀ tile: D[j=4q+r][i=i16] — feeds PV B-operand directly
            half4 pb[2];
            #pragma unroll
            for (int it = 0; it < 2; ++it) {
                float4v z = {0.f, 0.f, 0.f, 0.f};
                float4v s = __builtin_amdgcn_mfma_f32_16x16x32_f16(ka[jt], qb[it], z, 0, 0, 0);
                pb[it] = (half4){ (_Float16)exp2f(s[0] - lg[it]),
                                  (_Float16)exp2f(s[1] - lg[it]),
                                  (_Float16)exp2f(s[2] - lg[it]),
                                  (_Float16)exp2f(s[3] - lg[it]) };
            }
            // PV: O[c][i] += V[c][j] * P[j][i]  (A=V b64 from LDS, B=pb from regs)
            #pragma unroll
            for (int ct = 0; ct < 4; ++ct) {
                int c = 64 * wc + 16 * ct + i16;
                int off = c * 32 + (((2 * jt + (q >> 1)) ^ (c & 3)) * 8) + (q & 1) * 4;
                half4 va = *(const half4*)&v_lds[cur][off];
                #pragma unroll
                for (int it = 0; it < 2; ++it)
                    O[ct][it] = __builtin_amdgcn_mfma_f32_16x16x16f16(va, pb[it], O[ct][it], 0, 0, 0);
            }
        }

        if (t < NN / 32 - 1) STAGE_WRITE((t + 1) & 1);
        __syncthreads();
    }

    // epilogue: O already normalized; residual add
    const float* xb = x + (size_t)b * CC * NN;
    float* ob = out + (size_t)b * CC * NN;
    #pragma unroll
    for (int ct = 0; ct < 4; ++ct)
        #pragma unroll
        for (int it = 0; it < 2; ++it)
            #pragma unroll
            for (int r = 0; r < 4; ++r) {
                int c = 64 * wc + 16 * ct + 4 * q + r;
                size_t idx = (size_t)c * NN + qbase + 16 * it + i16;
                ob[idx] = xb[idx] + O[ct][it][r];
            }
}

extern "C" void kernel_launch(void* const* d_in, const int* in_sizes, int n_in,
                              void* d_out, int out_size, void* d_ws, size_t ws_size,
                              hipStream_t stream) {
    const float* x  = (const float*)d_in[0];
    const float* Wq = (const float*)d_in[1];
    const float* bq = (const float*)d_in[2];
    const float* Wk = (const float*)d_in[3];
    const float* bk = (const float*)d_in[4];
    const float* Wv = (const float*)d_in[5];
    const float* bv = (const float*)d_in[6];
    float* out = (float*)d_out;

    char* ws = (char*)d_ws;
    _Float16* Wh = (_Float16*)(ws);                 // 320*256*2 = 163840
    float*    bh = (float*)(ws + 163840);           // 1280
    _Float16* Qt = (_Float16*)(ws + 262144);        // 1 MB
    _Float16* Kt = (_Float16*)(ws + 1310720);       // 1 MB
    _Float16* Vh = (_Float16*)(ws + 2359296);       // 8 MB
    float*    L  = (float*)(ws + 10747904);         // 4*4*4096*4 = 256 KB

    prep_kernel<<<dim3(320), 64, 0, stream>>>(Wq, bq, Wk, bk, Wv, bv, Wh, bh);
    proj_kernel<<<dim3(NN / 32, BB), 256, 0, stream>>>(x, Wh, bh, Qt, Kt, Vh);
    rowstat_kernel<<<dim3(NN / 64, 4, BB), 256, 0, stream>>>(Qt, Kt, L);
    attn_kernel<<<dim3(256), 512, 0, stream>>>(x, Qt, Kt, Vh, L, out);
}